// Round 10
// baseline (155.808 us; speedup 1.0000x reference)
//
#include <hip/hip_runtime.h>
#include <math.h>

// ---------------------------------------------------------------------------
// AttentionAggregator round 10:
//  R9 post-mortem: source-interleave was a no-op (compiler already did it).
//  Real stall: both waves/SIMD phase-locked at the SAME block barrier ->
//  MFMA and VALU phases alternate with no cross-wave overlap (6375 cyc/iter
//  = 2304 MFMA + 1850 VALU + 2200 stall, serialized).
//  R10: two INDEPENDENT 4-wave blocks per CU (256 thr, 512 blocks) -> the
//  blocks' barriers are independent, so block B feeds the matrix pipe while
//  block A sits in exp/barrier (m114 overlap). Same 2 waves/SIMD.
//   - Vbuf 2x32KB/block; epilogue Ebuf aliases Vbuf[0] (dead after last iter
//     which uses buf 1) -> 64 KB/block = exactly 2 blocks/CU.
//   - DMA traffic 512 MB (~1.1 TB/s/XCD, well under L2 BW).
//   - load_ka hoisted before S^T for vmcnt slack. Else identical to R9.
// ---------------------------------------------------------------------------
#define NR 8192
#define DQ 32
#define DV 256
#define OUT_DIM 64
#define NSPLIT 4
#define BK 64
#define NIT ((NR / NSPLIT) / BK)      // 32
// 2^-1.25 * sqrt(log2(e)): qh = q*QS2 -> dot = (q.q')/sqrt(32)*log2(e); p=2^s
#define QSCALE2 0.5050114839784955f

typedef short short4v __attribute__((ext_vector_type(4)));
typedef short short8 __attribute__((ext_vector_type(8)));   // 8 bf16
typedef float f32x16 __attribute__((ext_vector_type(16)));  // 32x32 MFMA acc
typedef unsigned int u32;
typedef __attribute__((address_space(1))) const u32 gas_t;
typedef __attribute__((address_space(3))) u32 las_t;

__device__ __forceinline__ unsigned short f32_to_bf16(float f) {
    union { float f; unsigned int u; } v; v.f = f;
    unsigned int u = v.u + 0x7FFFu + ((v.u >> 16) & 1u);    // RNE
    return (unsigned short)(u >> 16);
}
__device__ __forceinline__ float exp2_fast(float x) {
#if __has_builtin(__builtin_amdgcn_exp2f)
    return __builtin_amdgcn_exp2f(x);
#else
    return exp2f(x);
#endif
}

// ---------------------------------------------------------------------------
// prep: [0,256) gather | [256,768) qconv | [768,784) wconv. No zeroing.
// ---------------------------------------------------------------------------
__global__ void prep_kernel(
        const float* __restrict__ review,
        const float* __restrict__ user,
        const float* __restrict__ item,
        const int* __restrict__ adj_ur, const int* __restrict__ adj_ri,
        const int* __restrict__ adj_ir, const int* __restrict__ adj_ru,
        const float* __restrict__ Wu,  const float* __restrict__ Wi,
        unsigned short* __restrict__ qh,
        unsigned short* __restrict__ wbf,
        unsigned short* __restrict__ vt) {
    __shared__ __align__(16) unsigned short T[64][264];
    int b = blockIdx.x, t = threadIdx.x;
    if (b < 256) {
        // ---- gather: one side x 64 keys -> one 32 KB permuted vt tile ----
        int side = b >> 7;
        int bxg  = b & 127;
        int key0 = bxg * 64;
        const int* adjA   = side ? adj_ir : adj_ur;
        const int* adjB   = side ? adj_ru : adj_ri;
        const float* srcB = side ? user : item;
        {
            int key = t >> 2, q = t & 3;
#pragma unroll
            for (int rr = 0; rr < 2; ++rr) {
                int ss  = q * 2 + rr;
                int knb = ss >> 1, isB = ss & 1;
                int row = (isB ? adjB : adjA)[(key0 + key) * 4 + knb];
                const float4* src = (const float4*)((isB ? srcB : review) + (size_t)row * DQ);
                int dbase = knb * 64 + isB * 32;
#pragma unroll
                for (int d = 0; d < 4; ++d) {
                    float4 a = src[d * 2], b2 = src[d * 2 + 1];
                    short8 v;
                    v[0] = (short)f32_to_bf16(a.x);  v[1] = (short)f32_to_bf16(a.y);
                    v[2] = (short)f32_to_bf16(a.z);  v[3] = (short)f32_to_bf16(a.w);
                    v[4] = (short)f32_to_bf16(b2.x); v[5] = (short)f32_to_bf16(b2.y);
                    v[6] = (short)f32_to_bf16(b2.z); v[7] = (short)f32_to_bf16(b2.w);
                    *(short8*)&T[key][dbase + d * 8] = v;
                }
            }
        }
        __syncthreads();
        // phase 2: permuted frag-native writes (R7/R8/R9-verified permutation):
        // B-frag (g,ct,lane=(ln,h),i) = V[32kt+16a+4h+8(i>>2)+(i&3)][ct*32+ln]
#pragma unroll
        for (int w8 = 0; w8 < 8; ++w8) {
            int u    = t + 256 * w8;          // 0..2047
            int g    = u >> 9;
            int ct   = (u >> 6) & 7;
            int lane = u & 63;
            int ln = lane & 31, h = lane >> 5;
            int kt = g >> 1, a = g & 1;
            int col = ct * 32 + ln;
            short8 v;
#pragma unroll
            for (int i = 0; i < 8; ++i) {
                int lkey = kt * 32 + a * 16 + h * 4 + 8 * (i >> 2) + (i & 3);
                v[i] = (short)T[lkey][col];
            }
            size_t dst = (size_t)side * NR * DV + (size_t)bxg * 16384 + (size_t)u * 8;
            *(short8*)(vt + dst) = v;
        }
        return;
    }
    b -= 256;
    if (b < 512) {                        // qconv
        int i = (b * 256 + t) * 4;
        int side  = i >= NR * DQ;
        int local = i - side * NR * DQ;
        const float* src = side ? item : user;
        float4 v = *(const float4*)(src + local);
        short4v o;
        o[0] = (short)f32_to_bf16(v.x * QSCALE2);
        o[1] = (short)f32_to_bf16(v.y * QSCALE2);
        o[2] = (short)f32_to_bf16(v.z * QSCALE2);
        o[3] = (short)f32_to_bf16(v.w * QSCALE2);
        *(short4v*)(qh + i) = o;
        return;
    }
    b -= 512;                             // wconv: wbf[wm][p][kt][nt][lane][i]
    int g  = b * 256 + t;
    int ln = g & 31, h = (g >> 5) & 1, nt = (g >> 6) & 1;
    int kt = (g >> 7) & 3, p = (g >> 9) & 3, wm = g >> 11;
    const float* W = wm ? Wi : Wu;
    unsigned short* dst = wbf + (size_t)g * 8;
#pragma unroll
    for (int i = 0; i < 8; ++i) {
        int k = p * 64 + kt * 16 + h * 8 + i;
        dst[i] = f32_to_bf16(W[k * OUT_DIM + nt * 32 + ln]);
    }
}

// ---------------------------------------------------------------------------
// Flash attention: 4-wave blocks (256 thr), 512 blocks = 2 independent
// blocks/CU (independent barriers -> cross-block MFMA/VALU overlap).
// bx&7 = side + 2*sp (XCD-affine), rb = bx>>3 (0..63). Wave = 32r x 256c.
// ---------------------------------------------------------------------------
__global__ __launch_bounds__(256, 2) void flash_kernel(
        const unsigned short* __restrict__ qh,
        const unsigned short* __restrict__ vt,
        const unsigned short* __restrict__ wbf,
        float* __restrict__ opart,   // [NSPLIT][2][NR][64]
        float* __restrict__ lpart)   // [NSPLIT][2][NR]
{
    const int bx   = blockIdx.x;
    const int side = bx & 1;
    const int sp   = (bx >> 1) & (NSPLIT - 1);
    const int rb   = bx >> 3;                  // 0..63
    const int w    = threadIdx.x >> 6;         // 0..3
    const int lane = threadIdx.x & 63;
    const int ln   = lane & 31;
    const int h    = lane >> 5;

    const int m0 = rb * 128 + w * 32;          // wave's first q-row
    const unsigned short* Q  = qh + (size_t)side * NR * DQ;
    const unsigned short* VT = vt + (size_t)side * NR * DV;
    const int t64_0 = sp * NIT;                // first 64-key tile index

    __shared__ __align__(16) unsigned short Vbuf[2][16384];   // 64 KB total
    // Epilogue scratch aliases Vbuf[0]: last iter (NIT-1=31, odd) reads buf 1,
    // so buf 0 is dead by the time the epilogue writes. 4 waves x 2304 shorts.
    unsigned short* Ew = &Vbuf[0][0] + w * (32 * 72);

    auto stage = [&](int tile, int b) {
        const unsigned short* src = VT + (size_t)tile * 16384 + w * 4096 + lane * 8;
        unsigned short* dst = &Vbuf[b][w * 4096];
#pragma unroll
        for (int k2 = 0; k2 < 8; ++k2)
            __builtin_amdgcn_global_load_lds((gas_t*)(src + k2 * 512),
                                             (las_t*)(dst + k2 * 512), 16, 0, 0);
    };
    auto load_ka = [&](int j0, short8* ka) {
#pragma unroll
        for (int kt = 0; kt < 2; ++kt)
#pragma unroll
            for (int dh = 0; dh < 2; ++dh)
                ka[kt * 2 + dh] = *(const short8*)(Q + (size_t)(j0 + kt * 32 + ln) * DQ
                                                   + dh * 16 + h * 8);
    };

    // persistent Q B-frags for this wave's 32 rows
    short8 bq[2];
#pragma unroll
    for (int dh = 0; dh < 2; ++dh)
        bq[dh] = *(const short8*)(Q + (size_t)(m0 + ln) * DQ + dh * 16 + h * 8);

    f32x16 zf;
#pragma unroll
    for (int r = 0; r < 16; ++r) zf[r] = 0.f;
    f32x16 o[8];
#pragma unroll
    for (int ct = 0; ct < 8; ++ct) o[ct] = zf;
    float l_acc = 0.f;

    short8 fr[4];
    short8 ka_buf[4];

    // exp chunk g: C regs [8a..8a+7] (a=g&1) -> fr[g] (PV A-frag, R7-verified)
    auto exp_chunk = [&](const f32x16& Cs, int g) {
        int a = g & 1;
        union { short8 s; u32 u[4]; } f;
#pragma unroll
        for (int j = 0; j < 4; ++j) {
            float e0 = exp2_fast(Cs[8 * a + 2 * j]);
            float e1 = exp2_fast(Cs[8 * a + 2 * j + 1]);
            l_acc += e0 + e1;
            u32 u0 = __builtin_bit_cast(u32, e0) + 0x8000u;
            u32 u1 = __builtin_bit_cast(u32, e1) + 0x8000u;
            f.u[j] = __builtin_amdgcn_perm(u1, u0, 0x07060302);
        }
        fr[g] = f.s;
    };

    // ---- prologue: fr for tile 0 ----
    {
        load_ka(t64_0 * 64, ka_buf);
        stage(t64_0, 0);
        f32x16 c0 = __builtin_amdgcn_mfma_f32_32x32x16_bf16(ka_buf[0], bq[0], zf, 0, 0, 0);
        c0 = __builtin_amdgcn_mfma_f32_32x32x16_bf16(ka_buf[1], bq[1], c0, 0, 0, 0);
        f32x16 c1 = __builtin_amdgcn_mfma_f32_32x32x16_bf16(ka_buf[2], bq[0], zf, 0, 0, 0);
        c1 = __builtin_amdgcn_mfma_f32_32x32x16_bf16(ka_buf[3], bq[1], c1, 0, 0, 0);
        exp_chunk(c0, 0); exp_chunk(c0, 1);
        exp_chunk(c1, 2); exp_chunk(c1, 3);
        load_ka(t64_0 * 64 + BK, ka_buf);    // K for tile 1
    }
    __syncthreads();                         // DMA(tile 0) landed

    for (int it = 0; it < NIT; ++it) {
        const int more = (it + 1 < NIT);
        f32x16 C0, C1;
        if (more) {
            stage(t64_0 + it + 1, (it + 1) & 1);
            if (it + 2 < NIT) {
                // hoisted: max slack before the barrier's forced vmcnt drain
                short8 ka_nx[4];
                load_ka((t64_0 + it + 2) * 64, ka_nx);
                C0 = __builtin_amdgcn_mfma_f32_32x32x16_bf16(ka_buf[0], bq[0], zf, 0, 0, 0);
                C0 = __builtin_amdgcn_mfma_f32_32x32x16_bf16(ka_buf[1], bq[1], C0, 0, 0, 0);
                C1 = __builtin_amdgcn_mfma_f32_32x32x16_bf16(ka_buf[2], bq[0], zf, 0, 0, 0);
                C1 = __builtin_amdgcn_mfma_f32_32x32x16_bf16(ka_buf[3], bq[1], C1, 0, 0, 0);
                ka_buf[0] = ka_nx[0]; ka_buf[1] = ka_nx[1];
                ka_buf[2] = ka_nx[2]; ka_buf[3] = ka_nx[3];
            } else {
                C0 = __builtin_amdgcn_mfma_f32_32x32x16_bf16(ka_buf[0], bq[0], zf, 0, 0, 0);
                C0 = __builtin_amdgcn_mfma_f32_32x32x16_bf16(ka_buf[1], bq[1], C0, 0, 0, 0);
                C1 = __builtin_amdgcn_mfma_f32_32x32x16_bf16(ka_buf[2], bq[0], zf, 0, 0, 0);
                C1 = __builtin_amdgcn_mfma_f32_32x32x16_bf16(ka_buf[3], bq[1], C1, 0, 0, 0);
            }
        }
        // ---- PV(it) with exp(it+1) refilling fr[g] after its last use ----
        const unsigned short* vb = &Vbuf[it & 1][0] + (size_t)lane * 8;
#pragma unroll
        for (int g = 0; g < 4; ++g) {
#pragma unroll
            for (int ct = 0; ct < 8; ++ct) {
                short8 bv = *(const short8*)(vb + (g * 8 + ct) * 512);
                o[ct] = __builtin_amdgcn_mfma_f32_32x32x16_bf16(fr[g], bv, o[ct], 0, 0, 0);
            }
            if (more) exp_chunk((g < 2) ? C0 : C1, g);
        }
        if (more) __syncthreads();   // next tile staged; all waves off old buf
    }

    // ---- l: q on lane axis -> one cross-half reduce; unique writer ----
    l_acc += __shfl_xor(l_acc, 32);
    if (h == 0)
        lpart[(size_t)(sp * 2 + side) * NR + m0 + ln] = l_acc;

    // ---- epilogue: 4 col-passes; O->bf16->Ew (aliases dead Vbuf[0]) ----
    f32x16 pp[2];
    pp[0] = zf; pp[1] = zf;
    const unsigned short* wb_base = wbf + (size_t)side * 16384;
#pragma unroll
    for (int p = 0; p < 4; ++p) {
        __builtin_amdgcn_s_waitcnt(0xC07F);   // prior pass's Ew reads landed
#pragma unroll
        for (int c2 = 0; c2 < 2; ++c2)
#pragma unroll
            for (int r = 0; r < 16; ++r) {
                int row = (r & 3) + ((r >> 2) << 3) + h * 4;
                Ew[row * 72 + c2 * 32 + ln] = f32_to_bf16(o[2 * p + c2][r]);
            }
#pragma unroll
        for (int kt = 0; kt < 4; ++kt) {
            short8 a = *(const short8*)&Ew[ln * 72 + kt * 16 + h * 8];
#pragma unroll
            for (int nt = 0; nt < 2; ++nt) {
                short8 bw = *(const short8*)(wb_base
                            + ((size_t)(p * 4 + kt) * 2 + nt) * 512 + (size_t)lane * 8);
                pp[nt] = __builtin_amdgcn_mfma_f32_32x32x16_bf16(a, bw, pp[nt], 0, 0, 0);
            }
        }
    }

    // ---- store projected partials (unique writer, no atomics) ----
    float* op = opart + ((size_t)(sp * 2 + side) * NR + m0) * OUT_DIM;
#pragma unroll
    for (int nt = 0; nt < 2; ++nt)
#pragma unroll
        for (int r = 0; r < 16; ++r) {
            int row = (r & 3) + ((r >> 2) << 3) + h * 4;
            op[(size_t)row * OUT_DIM + nt * 32 + ln] = pp[nt][r];
        }
}

// ---------------------------------------------------------------------------
// final: out = relu( (sum_sp opart) / (sum_sp lpart) ), float4 per thread.
// ---------------------------------------------------------------------------
__global__ void final_kernel(const float4* __restrict__ opart,
                             const float* __restrict__ lpart,
                             float4* __restrict__ out) {
    int i4  = blockIdx.x * blockDim.x + threadIdx.x;   // 0..262143
    int row = i4 >> 4;                                  // side*NR + m
    float4 v = make_float4(0.f, 0.f, 0.f, 0.f);
    float L = 0.f;
#pragma unroll
    for (int sp = 0; sp < NSPLIT; ++sp) {
        float4 a = opart[(size_t)sp * (2 * NR * 16) + i4];
        v.x += a.x; v.y += a.y; v.z += a.z; v.w += a.w;
        L += lpart[(size_t)sp * (2 * NR) + row];
    }
    float inv = 1.0f / L;
    out[i4] = make_float4(fmaxf(v.x * inv, 0.f), fmaxf(v.y * inv, 0.f),
                          fmaxf(v.z * inv, 0.f), fmaxf(v.w * inv, 0.f));
}

// ---------------------------------------------------------------------------
extern "C" void kernel_launch(void* const* d_in, const int* in_sizes, int n_in,
                              void* d_out, int out_size, void* d_ws, size_t ws_size,
                              hipStream_t stream) {
    const float* review = (const float*)d_in[0];
    const float* user   = (const float*)d_in[1];
    const float* item   = (const float*)d_in[2];
    const int* adj_ur   = (const int*)d_in[3];
    const int* adj_ri   = (const int*)d_in[4];
    const int* adj_ir   = (const int*)d_in[5];
    const int* adj_ru   = (const int*)d_in[6];
    const float* Wu     = (const float*)d_in[7];
    const float* Wi     = (const float*)d_in[8];
    float* out = (float*)d_out;

    // ws: opart 16MB | lpart 256KB | vt 8MB | qh 1MB | wbf 64KB  (~25.3 MB)
    float* opart = (float*)d_ws;
    float* lpart = opart + (size_t)NSPLIT * 2 * NR * OUT_DIM;
    unsigned short* vt  = (unsigned short*)(lpart + (size_t)NSPLIT * 2 * NR);
    unsigned short* qh  = vt + (size_t)2 * NR * DV;
    unsigned short* wbf = qh + (size_t)2 * NR * DQ;

    prep_kernel<<<784, 256, 0, stream>>>(
        review, user, item, adj_ur, adj_ri, adj_ir, adj_ru, Wu, Wi,
        qh, wbf, vt);
    flash_kernel<<<512, 256, 0, stream>>>(qh, vt, wbf, opart, lpart);
    final_kernel<<<1024, 256, 0, stream>>>((const float4*)opart, lpart, (float4*)out);
}